// Round 7
// baseline (1269.004 us; speedup 1.0000x reference)
//
#include <hip/hip_runtime.h>

// FullAttention fused block on gfx950 — SINGLE-KERNEL mega-fusion.
//
// r0-r6 evidence: total - attn ~= 96-103 us across ALL configurations while
// bottom-up kernel cost of the non-attn work is ~30 us -> ~60-70 us is
// inter-dispatch overhead (launch/ramp/drain + aux dispatches), reachable
// only by collapsing the launch structure. This kernel runs all 5 phases
// (prep -> qkv -> attn -> merge -> oproj), each phase byte-identical to its
// r6 kernel, separated by device-scope grid barriers.
//
// Co-residency (deadlock-free) by construction:
//   grid = 1024 blocks x 256 thr; __launch_bounds__(256,4) caps VGPR at 128
//   (16 waves/CU); static LDS = 32768 B (160K/32K = 5 blocks/CU >= 4);
//   1024 = 256 CU x 4 blocks exact -> all blocks resident.
// Barriers: monotonic counters (memset to 0 per launch via hipMemsetAsync),
// device-scope atomics + __threadfence release/acquire (cross-XCD G16).
//
// MFMA 16x16x32 layouts (HW-verified per guide):
//   A-frag: lane holds A[m=lane&15][k=quad*8+j], j=0..7
//   B-frag: lane holds B[k=quad*8+j][n=lane&15]
//   C/D   : lane holds D[row=quad*4+reg][col=lane&15], reg=0..3

#define NPIX 4096
#define CIN 256
#define INNER 512
#define NHEAD 8
#define DH 64
#define N1 (3 * INNER * CIN)  // 393216 (w_qkv elems); 393216 % 512 == 0
#define N2 (CIN * INNER)      // 131072 (w_out elems)
#define NBLK 1024u

typedef _Float16 f16;
typedef __attribute__((ext_vector_type(2))) _Float16 f16x2;
typedef __attribute__((ext_vector_type(4))) _Float16 f16x4;
typedef __attribute__((ext_vector_type(8))) _Float16 f16x8;
typedef __attribute__((ext_vector_type(4))) float f32x4;

static __device__ __forceinline__ f32x4 mfma_f16(f16x8 a, f16x8 b, f32x4 c) {
  return __builtin_amdgcn_mfma_f32_16x16x32_f16(a, b, c, 0, 0, 0);
}

static __device__ __forceinline__ unsigned pk2(float lo, float hi) {
  return __builtin_bit_cast(unsigned, __builtin_amdgcn_cvt_pkrtz(lo, hi));
}

// async global->LDS, 16 B per lane; LDS dest = wave-uniform base + lane*16
static __device__ __forceinline__ void gload_lds16(const void* g, void* l) {
  __builtin_amdgcn_global_load_lds(
      (const __attribute__((address_space(1))) unsigned*)g,
      (__attribute__((address_space(3))) unsigned*)l, 16, 0, 0);
}

// grid-wide barrier; all NBLK blocks are co-resident (see launch_bounds note).
static __device__ __forceinline__ void gbar(unsigned* bar, int idx) {
  __threadfence();  // release: drain + L2 writeback so other XCDs see our data
  __syncthreads();
  if (threadIdx.x == 0) {
    unsigned* c = bar + idx * 32;  // 128 B per counter
    __hip_atomic_fetch_add(c, 1u, __ATOMIC_RELEASE, __HIP_MEMORY_SCOPE_AGENT);
    while (__hip_atomic_load(c, __ATOMIC_ACQUIRE, __HIP_MEMORY_SCOPE_AGENT) <
           NBLK)
      __builtin_amdgcn_s_sleep(2);
  }
  __syncthreads();
  __threadfence();  // acquire: invalidate L1/L2 before reading remote data
}

__global__ __launch_bounds__(256, 4) void k_mega(
    const float* __restrict__ x, const float* __restrict__ nw,
    const float* __restrict__ w1, const float* __restrict__ w2,
    const float* __restrict__ bout, float* __restrict__ xn,
    f16* __restrict__ xnT, f16* __restrict__ wh,  // wh = [wqkv_h | wout_h]
    f16* __restrict__ qT, f16* __restrict__ kT, f16* __restrict__ vv,
    f16* __restrict__ Opart, float* __restrict__ Lpart, f16* __restrict__ Ows,
    float* __restrict__ out, unsigned* __restrict__ bar) {
  __shared__ char SMEM[32768];
  const int bid = blockIdx.x;
  const int tid = threadIdx.x;

  // ---------------- Phase P: RMSNorm (blocks 0..511) + weight cvt (all) ----
  {
    if (bid < NPIX / 8) {
      float(*red)[8] = reinterpret_cast<float(*)[8]>(SMEM);
      const int pi = tid & 7, cs = tid >> 3;  // 8 px x 32 ch-grp
      const int p = bid * 8 + pi;
      float xv[8];
      float ss = 0.f;
#pragma unroll
      for (int i = 0; i < 8; ++i) {
        xv[i] = x[(cs * 8 + i) * NPIX + p];
        ss += xv[i] * xv[i];
      }
      red[cs][pi] = ss;
      __syncthreads();
      float tot = 0.f;
#pragma unroll
      for (int s = 0; s < 32; ++s) tot += red[s][pi];
      float inv = 16.0f / fmaxf(sqrtf(tot), 1e-12f);  // sqrt(256)=16
      union { f16x8 v; f16 h[8]; } hv;
#pragma unroll
      for (int i = 0; i < 8; ++i) {
        int c = cs * 8 + i;
        float v = xv[i] * inv * nw[c];
        xn[c * NPIX + p] = v;
        hv.h[i] = (f16)v;
      }
      *(f16x8*)(xnT + (size_t)p * CIN + cs * 8) = hv.v;
    }
    // weight cvt: 524288 elems = 1024 blocks x 512; N1 % 512 == 0 so a
    // block's range never straddles the w1/w2 boundary.
    const int i = bid * 512 + tid * 2;
    const float* src = (i < N1) ? w1 : w2;
    const int off = (i < N1) ? i : i - N1;
    float2 v2 = *(const float2*)(src + off);
    f16x2 h2 = {(f16)v2.x, (f16)v2.y};
    *(f16x2*)(wh + i) = h2;
  }
  gbar(bar, 0);

  // ---------------- Phase Q: QKV GEMM (blocks 0..767), r6 k_qkv verbatim ---
  if (bid < 768) {
    const f16* wqkv = wh;
    const int bx = bid & 31, by = bid >> 5;
    const int lane = tid & 63, wave = tid >> 6;
    const int l15 = lane & 15, quad = lane >> 4;
    const int obase = by * 64 + (wave >> 1) * 32;
    const int pbase = bx * 128 + (wave & 1) * 64;
    const int sect = by >> 3;  // 0=q, 1=k, 2=v
    f32x4 acc[8];
#pragma unroll
    for (int i = 0; i < 8; ++i) acc[i] = (f32x4){0.f, 0.f, 0.f, 0.f};
#pragma unroll
    for (int kc = 0; kc < CIN / 32; ++kc) {
      f16x8 af[2], bfr[4];
#pragma unroll
      for (int oc = 0; oc < 2; ++oc)
        af[oc] = *(const f16x8*)(wqkv + (size_t)(obase + oc * 16 + l15) * CIN +
                                 kc * 32 + quad * 8);
#pragma unroll
      for (int pc = 0; pc < 4; ++pc)
        bfr[pc] = *(const f16x8*)(xnT + (size_t)(pbase + pc * 16 + l15) * CIN +
                                  kc * 32 + quad * 8);
      if (sect < 2) {
#pragma unroll
        for (int pc = 0; pc < 4; ++pc)
#pragma unroll
          for (int oc = 0; oc < 2; ++oc)
            acc[pc * 2 + oc] = mfma_f16(bfr[pc], af[oc], acc[pc * 2 + oc]);
      } else {
#pragma unroll
        for (int oc = 0; oc < 2; ++oc)
#pragma unroll
          for (int pc = 0; pc < 4; ++pc)
            acc[oc * 4 + pc] = mfma_f16(af[oc], bfr[pc], acc[oc * 4 + pc]);
      }
    }
    if (sect < 2) {
      f16* dst = (sect == 0) ? qT : kT;
      const float sc = (sect == 0) ? 0.18033688f : 1.0f;  // 0.125*log2(e)
      const int head = by & 7;
      const int dd = (wave >> 1) * 32;
#pragma unroll
      for (int pc = 0; pc < 4; ++pc)
#pragma unroll
        for (int oc = 0; oc < 2; ++oc)
#pragma unroll
          for (int r = 0; r < 4; ++r) {
            int p = pbase + pc * 16 + quad * 4 + r;
            dst[((size_t)(head << 12) + p) * DH + dd + oc * 16 + l15] =
                (f16)(acc[pc * 2 + oc][r] * sc);
          }
    } else {
#pragma unroll
      for (int oc = 0; oc < 2; ++oc)
#pragma unroll
        for (int r = 0; r < 4; ++r) {
          int o = obase + oc * 16 + quad * 4 + r - 2 * INNER;
#pragma unroll
          for (int pc = 0; pc < 4; ++pc)
            vv[(size_t)o * NPIX + pbase + pc * 16 + l15] =
                (f16)acc[oc * 4 + pc][r];
        }
    }
  }
  gbar(bar, 1);

  // ---------------- Phase A: flash attention (all 1024), r6 k_attn verbatim
  {
    f16(*KV)[8192] = reinterpret_cast<f16(*)[8192]>(SMEM);
    const int head = bid & 7, split = (bid >> 3) & 3, qb = bid >> 5;
    const int wave = tid >> 6, lane = tid & 63;
    const int l15 = lane & 15, quad = lane >> 4;
    const int keybase = split * 1024;

    const int qrow = (head << 12) + qb * 128 + wave * 32;
    f16x8 qf[2][2];
#pragma unroll
    for (int qt = 0; qt < 2; ++qt)
#pragma unroll
      for (int kc = 0; kc < 2; ++kc)
        qf[qt][kc] = *(const f16x8*)(qT + (size_t)(qrow + qt * 16 + l15) * DH +
                                     kc * 32 + quad * 8);

    f32x4 o[2][4];
    float ol[2] = {0.f, 0.f};
#pragma unroll
    for (int qt = 0; qt < 2; ++qt)
#pragma unroll
      for (int c = 0; c < 4; ++c) o[qt][c] = (f32x4){0.f, 0.f, 0.f, 0.f};

    const int rx = l15 & 7;
    const bool qodd = (quad & 1) != 0;

    const int sRow8 = lane >> 3, sCol = lane & 7;
    const f16* sp[4];
    const int step = (wave < 2) ? 64 * DH : 64;
#pragma unroll
    for (int j = 0; j < 4; ++j) {
      const int Rb = wave * 4096 + j * 1024;
      if (wave < 2) {
        const int key = (Rb >> 7) + sRow8;
        sp[j] = kT + ((size_t)(head << 12) + keybase + key) * DH +
                ((sCol ^ (key & 7)) << 3);
      } else {
        const int dd = ((Rb - 8192) >> 7) + sRow8;
        sp[j] = vv + ((size_t)(head * DH) + dd) * NPIX + keybase +
                ((sCol ^ (dd & 7)) << 3);
      }
    }
    auto stage = [&](int b) {
      char* base = (char*)(&KV[b][0]) + wave * 4096;
#pragma unroll
      for (int j = 0; j < 4; ++j) {
        gload_lds16(sp[j], base + j * 1024);
        sp[j] += step;
      }
    };

    stage(0);
    __syncthreads();

    for (int ch = 0; ch < 16; ++ch) {
      const int b = ch & 1;
      if (ch < 15) stage(b ^ 1);
      const f16* Kb = &KV[b][0];
      const f16* Vb = &KV[b][4096];
#pragma unroll
      for (int h = 0; h < 2; ++h) {
        f16x8 kf[2][2], vf[4];
#pragma unroll
        for (int nc = 0; nc < 2; ++nc) {
          const int key = h * 32 + nc * 16 + l15;
#pragma unroll
          for (int kc = 0; kc < 2; ++kc)
            kf[nc][kc] =
                *(const f16x8*)(Kb + key * 64 + (((kc * 4 + quad) ^ rx) << 3));
        }
#pragma unroll
        for (int c = 0; c < 4; ++c) {
          const int dd = c * 16 + l15;
          vf[c] = *(const f16x8*)(Vb + dd * 64 + (((h * 4 + quad) ^ rx) << 3));
        }
#pragma unroll
        for (int qt = 0; qt < 2; ++qt) {
          f32x4 s0 = mfma_f16(kf[0][0], qf[qt][0], (f32x4){0.f, 0.f, 0.f, 0.f});
          s0 = mfma_f16(kf[0][1], qf[qt][1], s0);
          f32x4 s1 = mfma_f16(kf[1][0], qf[qt][0], (f32x4){0.f, 0.f, 0.f, 0.f});
          s1 = mfma_f16(kf[1][1], qf[qt][1], s1);
          float p0[4], p1[4];
#pragma unroll
          for (int r = 0; r < 4; ++r) {
            p0[r] = __builtin_amdgcn_exp2f(s0[r]);
            p1[r] = __builtin_amdgcn_exp2f(s1[r]);
          }
          ol[qt] += ((p0[0] + p0[1]) + (p0[2] + p0[3])) +
                    ((p1[0] + p1[1]) + (p1[2] + p1[3]));
          unsigned A0 = pk2(p0[0], p0[1]), B0 = pk2(p0[2], p0[3]);
          unsigned A1 = pk2(p1[0], p1[1]), B1 = pk2(p1[2], p1[3]);
          asm("v_permlane16_swap_b32 %0, %1" : "+v"(A0), "+v"(A1));
          asm("v_permlane16_swap_b32 %0, %1" : "+v"(B0), "+v"(B1));
          unsigned xa = A0, ya = A0;
          asm("v_permlane32_swap_b32 %0, %1" : "+v"(xa), "+v"(ya));
          unsigned xa2 = A1, ya2 = A1;
          asm("v_permlane32_swap_b32 %0, %1" : "+v"(xa2), "+v"(ya2));
          unsigned xb = B0, yb = B0;
          asm("v_permlane32_swap_b32 %0, %1" : "+v"(xb), "+v"(yb));
          unsigned xb2 = B1, yb2 = B1;
          asm("v_permlane32_swap_b32 %0, %1" : "+v"(xb2), "+v"(yb2));
          union { f16x8 v; unsigned u[4]; } pf;
          pf.u[0] = qodd ? ya : xa;
          pf.u[1] = qodd ? yb : xb;
          pf.u[2] = qodd ? ya2 : xa2;
          pf.u[3] = qodd ? yb2 : xb2;
#pragma unroll
          for (int c = 0; c < 4; ++c) o[qt][c] = mfma_f16(vf[c], pf.v, o[qt][c]);
        }
      }
      __syncthreads();
    }

#pragma unroll
    for (int qt = 0; qt < 2; ++qt) {
      ol[qt] += __shfl_xor(ol[qt], 16);
      ol[qt] += __shfl_xor(ol[qt], 32);
    }

#pragma unroll
    for (int qt = 0; qt < 2; ++qt) {
#pragma unroll
      for (int c = 0; c < 4; ++c) {
        const size_t off = ((size_t)split * 32768 + qrow + qt * 16 + l15) * 64 +
                           c * 16 + quad * 4;
        f16x4 hv = {(f16)o[qt][c][0], (f16)o[qt][c][1], (f16)o[qt][c][2],
                    (f16)o[qt][c][3]};
        *(f16x4*)(Opart + off) = hv;
      }
      if (quad == 0) Lpart[split * 32768 + qrow + qt * 16 + l15] = ol[qt];
    }
  }
  gbar(bar, 2);

  // ---------------- Phase M: merge key-split partials (blocks 0..511) ------
  if (bid < 512) {
    const int tg = bid * 256 + tid;
    const int qi = tg >> 2;
    const size_t base = (size_t)tg * 16;
    float acc[16];
#pragma unroll
    for (int i = 0; i < 16; ++i) acc[i] = 0.f;
    float L = 0.f;
#pragma unroll
    for (int s = 0; s < 4; ++s) {
      const f16x8* ph = (const f16x8*)(Opart + (size_t)s * (32768 * 64) + base);
      f16x8 v0 = ph[0], v1 = ph[1];
#pragma unroll
      for (int i = 0; i < 8; ++i) {
        acc[i] += (float)v0[i];
        acc[8 + i] += (float)v1[i];
      }
      L += Lpart[s * 32768 + qi];
    }
    const float rL = 1.0f / L;
    union { f16x8 v[2]; f16 h[16]; } hv;
#pragma unroll
    for (int i = 0; i < 16; ++i) hv.h[i] = (f16)(acc[i] * rL);
    *(f16x8*)(Ows + base) = hv.v[0];
    *(f16x8*)(Ows + base + 8) = hv.v[1];
  }
  gbar(bar, 3);

  // ---------------- Phase O: out projection + bias + residual (0..511) -----
  if (bid < 512) {
    const f16* wout = wh + N1;
    const int bx = bid & 63, by = bid >> 6;
    const int lane = tid & 63, wave = tid >> 6;
    const int l15 = lane & 15, quad = lane >> 4;
    const int mbase = by * 32 + (wave >> 1) * 16;
    const int pbase = bx * 64 + (wave & 1) * 32;
    f32x4 acc[2];
    acc[0] = (f32x4){0.f, 0.f, 0.f, 0.f};
    acc[1] = (f32x4){0.f, 0.f, 0.f, 0.f};
#pragma unroll
    for (int kc = 0; kc < INNER / 32; ++kc) {
      f16x8 af = *(const f16x8*)(wout + (size_t)(mbase + l15) * INNER +
                                 kc * 32 + quad * 8);
      int i0 = kc * 32 + quad * 8;
      int head = i0 >> 6, d0 = i0 & 63;
#pragma unroll
      for (int pc = 0; pc < 2; ++pc) {
        f16x8 bfr = *(const f16x8*)(Ows + ((size_t)(head << 12) + pbase +
                                           pc * 16 + l15) * DH + d0);
        acc[pc] = mfma_f16(af, bfr, acc[pc]);
      }
    }
#pragma unroll
    for (int pc = 0; pc < 2; ++pc)
#pragma unroll
      for (int r = 0; r < 4; ++r) {
        int c = mbase + quad * 4 + r, p = pbase + pc * 16 + l15;
        out[c * NPIX + p] = acc[pc][r] + bout[c] + xn[c * NPIX + p];
      }
  }
}

extern "C" void kernel_launch(void* const* d_in, const int* in_sizes, int n_in,
                              void* d_out, int out_size, void* d_ws,
                              size_t ws_size, hipStream_t stream) {
  (void)in_sizes; (void)n_in; (void)out_size; (void)ws_size;
  const float* x      = (const float*)d_in[0];
  const float* norm_w = (const float*)d_in[1];
  const float* w_qkv  = (const float*)d_in[2];
  const float* w_out  = (const float*)d_in[3];
  const float* b_out  = (const float*)d_in[4];
  float* out = (float*)d_out;

  char* ws = (char*)d_ws;
  float* xn    = (float*)(ws);                 // 4 MB
  f16* xnT     = (f16*)(ws + (4u << 20));      // 2 MB
  f16* qT      = (f16*)(ws + (6u << 20));      // 4 MB  [head][p][d], pre-scaled
  f16* kT      = (f16*)(ws + (10u << 20));     // 4 MB  [head][p][d]
  f16* vv      = (f16*)(ws + (14u << 20));     // 4 MB  [head*64+d][p]
  f16* Ows     = (f16*)(ws + (18u << 20));     // 4 MB  [head][p][d]
  f16* wh      = (f16*)(ws + (22u << 20));     // 1 MB  [wqkv_h | wout_h]
  f16* Opart   = (f16*)(ws + (24u << 20));     // 16 MB [4][32768][64]
  float* Lpart = (float*)(ws + (40u << 20));   // 0.5 MB [4][32768]
  unsigned* bar = (unsigned*)(ws + (41u << 20));  // 4 x 128 B barrier counters

  hipMemsetAsync(bar, 0, 512, stream);
  hipLaunchKernelGGL(k_mega, dim3(1024), dim3(256), 0, stream,
                     x, norm_w, w_qkv, w_out, b_out, xn, xnT, wh,
                     qT, kT, vv, Opart, Lpart, Ows, out, bar);
}

// Round 8
// 167.490 us; speedup vs baseline: 7.5766x; 7.5766x over previous
//
#include <hip/hip_runtime.h>

// FullAttention fused block on gfx950. fp32 harness I/O, fp16 MFMA internally.
//
// Pipeline (5 launches; r7's single-kernel mega-fusion regressed 8x — the
// grid-barrier spin's agent-scope ACQUIRE load invalidates L1/L2 every
// iteration on gfx950's non-coherent-L2 topology -> reverted to r6 structure):
//   k_prep    : fused [rmsnorm: x[C][N] -> xn fp32 + xnT[N][C] f16] +
//               [w_qkv,w_out fp32 -> f16]; block-range split
//   k_qkv     : GEMM 1536x256x4096 -> qT/kT [head][p][d] f16 (q pre-scaled by
//               0.125*log2e), vv [d'][p] f16
//   k_attn    : flash attention. r6 PMC: pipe tally MFMA 33k + VALU 28k +
//               trans 16k + LDS 48k ~= wall 122k cyc -> zero inter-pipe
//               overlap (per-chunk barrier convoys all waves through the
//               same phase). This round: wave-parity h-stagger (waves 2,3
//               process key-halves in reverse order -> half the waves read
//               LDS while half run softmax/PV) + setprio around MFMA
//               clusters (T5: now has wave role diversity to arbitrate).
//   k_merge   : sum 4 key-split f16 partials, scale by 1/lsum -> Ows f16
//   k_oproj   : GEMM 256x512x4096 + bias + residual -> fp32 out
//
// MFMA 16x16x32 layouts (HW-verified per guide):
//   A-frag: lane holds A[m=lane&15][k=quad*8+j], j=0..7
//   B-frag: lane holds B[k=quad*8+j][n=lane&15]
//   C/D   : lane holds D[row=quad*4+reg][col=lane&15], reg=0..3

#define NPIX 4096
#define CIN 256
#define INNER 512
#define NHEAD 8
#define DH 64

typedef _Float16 f16;
typedef __attribute__((ext_vector_type(8))) _Float16 f16x8;
typedef __attribute__((ext_vector_type(4))) _Float16 f16x4;
typedef __attribute__((ext_vector_type(2))) _Float16 f16x2;
typedef __attribute__((ext_vector_type(4))) float f32x4;

static __device__ __forceinline__ f32x4 mfma_f16(f16x8 a, f16x8 b, f32x4 c) {
  return __builtin_amdgcn_mfma_f32_16x16x32_f16(a, b, c, 0, 0, 0);
}

static __device__ __forceinline__ unsigned pk2(float lo, float hi) {
  return __builtin_bit_cast(unsigned, __builtin_amdgcn_cvt_pkrtz(lo, hi));
}

// async global->LDS, 16 B per lane; LDS dest = wave-uniform base + lane*16
static __device__ __forceinline__ void gload_lds16(const void* g, void* l) {
  __builtin_amdgcn_global_load_lds(
      (const __attribute__((address_space(1))) unsigned*)g,
      (__attribute__((address_space(3))) unsigned*)l, 16, 0, 0);
}

// ---------------- K0: fused RMSNorm + weight cvt ----------------
// blocks [0,512): rmsnorm, 8 pixels each. blocks [512,2560): fp32->f16 cvt.
__global__ __launch_bounds__(256) void k_prep(
    const float* __restrict__ x, const float* __restrict__ w,
    float* __restrict__ xn, f16* __restrict__ xnT,
    const float* __restrict__ w1, int n1,
    const float* __restrict__ w2, int n2, f16* __restrict__ wh) {
  const int b = blockIdx.x;
  if (b < NPIX / 8) {
    const int pi = threadIdx.x & 7, cs = threadIdx.x >> 3;  // 8 px x 32 ch-grp
    const int p = b * 8 + pi;
    __shared__ float red[32][8];
    float xv[8];
    float ss = 0.f;
#pragma unroll
    for (int i = 0; i < 8; ++i) {
      xv[i] = x[(cs * 8 + i) * NPIX + p];
      ss += xv[i] * xv[i];
    }
    red[cs][pi] = ss;
    __syncthreads();
    float tot = 0.f;
#pragma unroll
    for (int s = 0; s < 32; ++s) tot += red[s][pi];
    float inv = 16.0f / fmaxf(sqrtf(tot), 1e-12f);  // sqrt(256)=16
    union { f16x8 v; f16 h[8]; } hv;
#pragma unroll
    for (int i = 0; i < 8; ++i) {
      int c = cs * 8 + i;
      float v = xv[i] * inv * w[c];
      xn[c * NPIX + p] = v;
      hv.h[i] = (f16)v;
    }
    *(f16x8*)(xnT + (size_t)p * CIN + cs * 8) = hv.v;
  } else {
    int i = (b - NPIX / 8) * 256 + threadIdx.x;
    if (i < n1) wh[i] = (f16)w1[i];
    else if (i < n1 + n2) wh[i] = (f16)w2[i - n1];
  }
}

// ---------------- K2: QKV GEMM, wave tile 32x64 ----------------
__global__ __launch_bounds__(256) void k_qkv(const f16* __restrict__ wqkv,
                                             const f16* __restrict__ xnT,
                                             f16* __restrict__ qT,
                                             f16* __restrict__ kT,
                                             f16* __restrict__ vv) {
  const int lane = threadIdx.x & 63, wave = threadIdx.x >> 6;
  const int l15 = lane & 15, quad = lane >> 4;
  const int obase = blockIdx.y * 64 + (wave >> 1) * 32;
  const int pbase = blockIdx.x * 128 + (wave & 1) * 64;
  const int sect = blockIdx.y >> 3;  // 0=q, 1=k, 2=v
  f32x4 acc[8];
#pragma unroll
  for (int i = 0; i < 8; ++i) acc[i] = (f32x4){0.f, 0.f, 0.f, 0.f};
#pragma unroll
  for (int kc = 0; kc < CIN / 32; ++kc) {
    f16x8 af[2], bfr[4];
#pragma unroll
    for (int oc = 0; oc < 2; ++oc)
      af[oc] = *(const f16x8*)(wqkv + (size_t)(obase + oc * 16 + l15) * CIN + kc * 32 + quad * 8);
#pragma unroll
    for (int pc = 0; pc < 4; ++pc)
      bfr[pc] = *(const f16x8*)(xnT + (size_t)(pbase + pc * 16 + l15) * CIN + kc * 32 + quad * 8);
    if (sect < 2) {
#pragma unroll
      for (int pc = 0; pc < 4; ++pc)
#pragma unroll
        for (int oc = 0; oc < 2; ++oc)
          acc[pc * 2 + oc] = mfma_f16(bfr[pc], af[oc], acc[pc * 2 + oc]);
    } else {
#pragma unroll
      for (int oc = 0; oc < 2; ++oc)
#pragma unroll
        for (int pc = 0; pc < 4; ++pc)
          acc[oc * 4 + pc] = mfma_f16(af[oc], bfr[pc], acc[oc * 4 + pc]);
    }
  }
  if (sect < 2) {
    f16* dst = (sect == 0) ? qT : kT;
    const float sc = (sect == 0) ? 0.18033688f : 1.0f;  // 0.125*log2(e)
    const int head = blockIdx.y & 7;
    const int dd = (wave >> 1) * 32;
#pragma unroll
    for (int pc = 0; pc < 4; ++pc)
#pragma unroll
      for (int oc = 0; oc < 2; ++oc)
#pragma unroll
        for (int r = 0; r < 4; ++r) {
          int p = pbase + pc * 16 + quad * 4 + r;
          dst[((size_t)(head << 12) + p) * DH + dd + oc * 16 + l15] =
              (f16)(acc[pc * 2 + oc][r] * sc);
        }
  } else {
#pragma unroll
    for (int oc = 0; oc < 2; ++oc)
#pragma unroll
      for (int r = 0; r < 4; ++r) {
        int o = obase + oc * 16 + quad * 4 + r - 2 * INNER;
#pragma unroll
        for (int pc = 0; pc < 4; ++pc)
          vv[(size_t)o * NPIX + pbase + pc * 16 + l15] = (f16)acc[oc * 4 + pc][r];
      }
  }
}

// ---------------- K3 helper: one 32-key half (compile-time H) ----------------
// Static H keeps all LDS addresses compile-time (rule #20: no scratch).
template <int H>
static __device__ __forceinline__ void attn_h(const f16* Kb, const f16* Vb,
                                              const f16x8 (&qf)[2][2],
                                              f32x4 (&o)[2][4], float (&ol)[2],
                                              int l15, int quad, int rx,
                                              bool qodd) {
  f16x8 kf[2][2], vf[4];
#pragma unroll
  for (int nc = 0; nc < 2; ++nc) {
    const int key = H * 32 + nc * 16 + l15;
#pragma unroll
    for (int kc = 0; kc < 2; ++kc)
      kf[nc][kc] = *(const f16x8*)(Kb + key * 64 + (((kc * 4 + quad) ^ rx) << 3));
  }
#pragma unroll
  for (int c = 0; c < 4; ++c) {
    const int dd = c * 16 + l15;
    vf[c] = *(const f16x8*)(Vb + dd * 64 + (((H * 4 + quad) ^ rx) << 3));
  }
#pragma unroll
  for (int qt = 0; qt < 2; ++qt) {
    // S^T[key][q] = K @ Q'^T (q pre-scaled; C-layout row=key, col=q)
    __builtin_amdgcn_s_setprio(1);
    f32x4 s0 = mfma_f16(kf[0][0], qf[qt][0], (f32x4){0.f, 0.f, 0.f, 0.f});
    s0 = mfma_f16(kf[0][1], qf[qt][1], s0);
    f32x4 s1 = mfma_f16(kf[1][0], qf[qt][0], (f32x4){0.f, 0.f, 0.f, 0.f});
    s1 = mfma_f16(kf[1][1], qf[qt][1], s1);
    __builtin_amdgcn_s_setprio(0);
    // p = exp2(s'), no max subtraction (|s'| << 1)
    float p0[4], p1[4];
#pragma unroll
    for (int r = 0; r < 4; ++r) {
      p0[r] = __builtin_amdgcn_exp2f(s0[r]);
      p1[r] = __builtin_amdgcn_exp2f(s1[r]);
    }
    // per-lane lsum partial; quad-reduce deferred to epilogue
    ol[qt] += ((p0[0] + p0[1]) + (p0[2] + p0[3])) +
              ((p1[0] + p1[1]) + (p1[2] + p1[3]));
    // P^T C-layout -> B-frag, pure VALU permlane network (r5-verified,
    // bank conflicts -> 0):
    unsigned A0 = pk2(p0[0], p0[1]), B0 = pk2(p0[2], p0[3]);
    unsigned A1 = pk2(p1[0], p1[1]), B1 = pk2(p1[2], p1[3]);
    asm("v_permlane16_swap_b32 %0, %1" : "+v"(A0), "+v"(A1));
    asm("v_permlane16_swap_b32 %0, %1" : "+v"(B0), "+v"(B1));
    unsigned xa = A0, ya = A0;
    asm("v_permlane32_swap_b32 %0, %1" : "+v"(xa), "+v"(ya));
    unsigned xa2 = A1, ya2 = A1;
    asm("v_permlane32_swap_b32 %0, %1" : "+v"(xa2), "+v"(ya2));
    unsigned xb = B0, yb = B0;
    asm("v_permlane32_swap_b32 %0, %1" : "+v"(xb), "+v"(yb));
    unsigned xb2 = B1, yb2 = B1;
    asm("v_permlane32_swap_b32 %0, %1" : "+v"(xb2), "+v"(yb2));
    union { f16x8 v; unsigned u[4]; } pf;
    pf.u[0] = qodd ? ya : xa;
    pf.u[1] = qodd ? yb : xb;
    pf.u[2] = qodd ? ya2 : xa2;
    pf.u[3] = qodd ? yb2 : xb2;
    // O^T[d][q] += V^T @ P^T
    __builtin_amdgcn_s_setprio(1);
#pragma unroll
    for (int c = 0; c < 4; ++c) o[qt][c] = mfma_f16(vf[c], pf.v, o[qt][c]);
    __builtin_amdgcn_s_setprio(0);
  }
}

// ---------------- K3: flash attention (LDS-staged K/V, q-split waves) --------
// grid 1024 x 256 threads. bid -> head = bid&7 (one head per XCD L2), split =
// (bid>>3)&3 (key quarter), qb = bid>>5 (0..31). Block: 4 waves x 32 q; keys
// [split*1024, +1024) staged through LDS in 16 double-buffered 64-key chunks.
// LDS swizzle conflict-free (r5 PMC: 0). Wave-parity h-stagger: waves 0,1
// process h=0,1; waves 2,3 process h=1,0 -> de-convoys the per-chunk phases
// so LDS reads of one half overlap softmax/PV of the other.
__global__ __launch_bounds__(256, 4) void k_attn(const f16* __restrict__ qT,
                                                 const f16* __restrict__ kT,
                                                 const f16* __restrict__ vv,
                                                 f16* __restrict__ Opart,
                                                 float* __restrict__ Lpart) {
  const int bid = blockIdx.x;
  const int head = bid & 7, split = (bid >> 3) & 3, qb = bid >> 5;
  const int tid = threadIdx.x;
  const int wave = tid >> 6, lane = tid & 63;
  const int l15 = lane & 15, quad = lane >> 4;
  const int keybase = split * 1024;

  __shared__ f16 KV[2][8192];  // per buf: [0,4096) = K chunk, [4096,8192) = V

  // Q B-frags: B[k=d][n=q] from qT[head][q][d]
  const int qrow = (head << 12) + qb * 128 + wave * 32;
  f16x8 qf[2][2];
#pragma unroll
  for (int qt = 0; qt < 2; ++qt)
#pragma unroll
    for (int kc = 0; kc < 2; ++kc)
      qf[qt][kc] = *(const f16x8*)(qT + (size_t)(qrow + qt * 16 + l15) * DH + kc * 32 + quad * 8);

  f32x4 o[2][4];
  float ol[2] = {0.f, 0.f};
#pragma unroll
  for (int qt = 0; qt < 2; ++qt)
#pragma unroll
    for (int c = 0; c < 4; ++c) o[qt][c] = (f32x4){0.f, 0.f, 0.f, 0.f};

  const int rx = l15 & 7;  // read-side swizzle xor (row&7 == l15&7)
  const bool qodd = (quad & 1) != 0;

  // staging pointers: waves 0,1 stage K rows; waves 2,3 stage V rows.
  const int sRow8 = lane >> 3, sCol = lane & 7;
  const f16* sp[4];
  const int step = (wave < 2) ? 64 * DH : 64;  // f16 elements per chunk
#pragma unroll
  for (int j = 0; j < 4; ++j) {
    const int Rb = wave * 4096 + j * 1024;  // LDS byte offset of this region
    if (wave < 2) {
      const int key = (Rb >> 7) + sRow8;  // 0..63
      sp[j] = kT + ((size_t)(head << 12) + keybase + key) * DH + ((sCol ^ (key & 7)) << 3);
    } else {
      const int dd = ((Rb - 8192) >> 7) + sRow8;  // 0..63
      sp[j] = vv + ((size_t)(head * DH) + dd) * NPIX + keybase + ((sCol ^ (dd & 7)) << 3);
    }
  }
  auto stage = [&](int b) {
    char* base = (char*)(&KV[b][0]) + wave * 4096;
#pragma unroll
    for (int j = 0; j < 4; ++j) {
      gload_lds16(sp[j], base + j * 1024);
      sp[j] += step;
    }
  };

  stage(0);
  __syncthreads();

  const bool hswap = wave >= 2;
  for (int ch = 0; ch < 16; ++ch) {
    const int b = ch & 1;
    if (ch < 15) stage(b ^ 1);  // issue early; drains under compute
    const f16* Kb = &KV[b][0];
    const f16* Vb = &KV[b][4096];
    if (!hswap) {
      attn_h<0>(Kb, Vb, qf, o, ol, l15, quad, rx, qodd);
      attn_h<1>(Kb, Vb, qf, o, ol, l15, quad, rx, qodd);
    } else {
      attn_h<1>(Kb, Vb, qf, o, ol, l15, quad, rx, qodd);
      attn_h<0>(Kb, Vb, qf, o, ol, l15, quad, rx, qodd);
    }
    __syncthreads();  // staged writes visible + all waves done with buf b
  }

  // deferred lsum quad-reduce
#pragma unroll
  for (int qt = 0; qt < 2; ++qt) {
    ol[qt] += __shfl_xor(ol[qt], 16);
    ol[qt] += __shfl_xor(ol[qt], 32);
  }

  // store partials (f16): Opart[split][qinst][d], Lpart[split][qinst]
#pragma unroll
  for (int qt = 0; qt < 2; ++qt) {
#pragma unroll
    for (int c = 0; c < 4; ++c) {
      const size_t off =
          ((size_t)split * 32768 + qrow + qt * 16 + l15) * 64 + c * 16 + quad * 4;
      f16x4 hv = {(f16)o[qt][c][0], (f16)o[qt][c][1], (f16)o[qt][c][2],
                  (f16)o[qt][c][3]};
      *(f16x4*)(Opart + off) = hv;
    }
    if (quad == 0) Lpart[split * 32768 + qrow + qt * 16 + l15] = ol[qt];
  }
}

// ---------------- K3b: merge 4 key-split f16 partials ----------------
__global__ __launch_bounds__(256) void k_merge(const f16* __restrict__ Opart,
                                               const float* __restrict__ Lpart,
                                               f16* __restrict__ Ows) {
  const int tg = blockIdx.x * 256 + threadIdx.x;
  const int qi = tg >> 2;
  const size_t base = (size_t)tg * 16;
  float acc[16];
#pragma unroll
  for (int i = 0; i < 16; ++i) acc[i] = 0.f;
  float L = 0.f;
#pragma unroll
  for (int s = 0; s < 4; ++s) {
    const f16x8* ph = (const f16x8*)(Opart + (size_t)s * (32768 * 64) + base);
    f16x8 v0 = ph[0], v1 = ph[1];
#pragma unroll
    for (int i = 0; i < 8; ++i) {
      acc[i] += (float)v0[i];
      acc[8 + i] += (float)v1[i];
    }
    L += Lpart[s * 32768 + qi];
  }
  const float rL = 1.0f / L;
  union { f16x8 v[2]; f16 h[16]; } hv;
#pragma unroll
  for (int i = 0; i < 16; ++i) hv.h[i] = (f16)(acc[i] * rL);
  *(f16x8*)(Ows + base) = hv.v[0];
  *(f16x8*)(Ows + base + 8) = hv.v[1];
}

// ---------------- K4: out projection + bias + residual ----------------
__global__ __launch_bounds__(256) void k_oproj(const f16* __restrict__ wout,
                                               const f16* __restrict__ Ows,
                                               const float* __restrict__ bout,
                                               const float* __restrict__ xn,
                                               float* __restrict__ out) {
  const int lane = threadIdx.x & 63, wave = threadIdx.x >> 6;
  const int l15 = lane & 15, quad = lane >> 4;
  const int mbase = blockIdx.y * 32 + (wave >> 1) * 16;
  const int pbase = blockIdx.x * 64 + (wave & 1) * 32;
  f32x4 acc[2];
  acc[0] = (f32x4){0.f, 0.f, 0.f, 0.f};
  acc[1] = (f32x4){0.f, 0.f, 0.f, 0.f};
#pragma unroll
  for (int kc = 0; kc < INNER / 32; ++kc) {
    f16x8 af = *(const f16x8*)(wout + (size_t)(mbase + l15) * INNER + kc * 32 + quad * 8);
    int i0 = kc * 32 + quad * 8;
    int head = i0 >> 6, d0 = i0 & 63;
#pragma unroll
    for (int pc = 0; pc < 2; ++pc) {
      f16x8 bfr = *(const f16x8*)(Ows + ((size_t)(head << 12) + pbase + pc * 16 + l15) * DH + d0);
      acc[pc] = mfma_f16(af, bfr, acc[pc]);
    }
  }
#pragma unroll
  for (int pc = 0; pc < 2; ++pc)
#pragma unroll
    for (int r = 0; r < 4; ++r) {
      int c = mbase + quad * 4 + r, p = pbase + pc * 16 + l15;
      out[c * NPIX + p] = acc[pc][r] + bout[c] + xn[c * NPIX + p];
    }
}

extern "C" void kernel_launch(void* const* d_in, const int* in_sizes, int n_in,
                              void* d_out, int out_size, void* d_ws, size_t ws_size,
                              hipStream_t stream) {
  (void)in_sizes; (void)n_in; (void)out_size; (void)ws_size;
  const float* x      = (const float*)d_in[0];
  const float* norm_w = (const float*)d_in[1];
  const float* w_qkv  = (const float*)d_in[2];
  const float* w_out  = (const float*)d_in[3];
  const float* b_out  = (const float*)d_in[4];
  float* out = (float*)d_out;

  char* ws = (char*)d_ws;
  float* xn    = (float*)(ws);                 // 4 MB
  f16* xnT     = (f16*)(ws + (4u << 20));      // 2 MB
  f16* qT      = (f16*)(ws + (6u << 20));      // 4 MB  [head][p][d], pre-scaled
  f16* kT      = (f16*)(ws + (10u << 20));     // 4 MB  [head][p][d]
  f16* vv      = (f16*)(ws + (14u << 20));     // 4 MB  [head*64+d][p]
  f16* Ows     = (f16*)(ws + (18u << 20));     // 4 MB  [head][p][d]
  f16* wqkv_h  = (f16*)(ws + (22u << 20));             // 0.75 MB
  f16* wout_h  = (f16*)(ws + (22u << 20) + 786432);    // 0.25 MB
  f16* Opart   = (f16*)(ws + (24u << 20));             // 16 MB [4][32768][64]
  float* Lpart = (float*)(ws + (40u << 20));           // 0.5 MB [4][32768]

  const int n1 = 3 * INNER * CIN, n2 = CIN * INNER;
  hipLaunchKernelGGL(k_prep, dim3(NPIX / 8 + (n1 + n2 + 255) / 256), dim3(256), 0,
                     stream, x, norm_w, xn, xnT, w_qkv, n1, w_out, n2, wqkv_h);
  hipLaunchKernelGGL(k_qkv, dim3(NPIX / 128, 1536 / 64), dim3(256), 0, stream,
                     wqkv_h, xnT, qT, kT, vv);
  hipLaunchKernelGGL(k_attn, dim3(1024), dim3(256), 0, stream,
                     qT, kT, vv, Opart, Lpart);
  hipLaunchKernelGGL(k_merge, dim3(512), dim3(256), 0, stream, Opart, Lpart, Ows);
  hipLaunchKernelGGL(k_oproj, dim3(NPIX / 64, CIN / 32), dim3(256), 0, stream,
                     wout_h, Ows, b_out, xn, out);
}

// Round 10
// 153.028 us; speedup vs baseline: 8.2927x; 1.0945x over previous
//
#include <hip/hip_runtime.h>

// FullAttention fused block on gfx950. fp32 harness I/O, fp16 MFMA internally.
//
// Pipeline (5 launches; r7 mega-fusion regressed 8x — grid-barrier spin with
// agent-scope acquire invalidates L1/L2 per iteration; r8 h-stagger+setprio
// regressed (m190 regime: setprio hurts barrier-synced lockstep blocks)):
//   k_prep    : fused [rmsnorm: x[C][N] -> xn fp32 + xnT[N][C] f16] +
//               [w_qkv,w_out fp32 -> f16]; block-range split
//   k_qkv     : GEMM 1536x256x4096 -> qT/kT [head][p][d] f16 (q pre-scaled by
//               0.125*log2e), vv [d'][p] f16
//   k_attn    : flash attention. r6 pipe audit: VALU 61k cyc/CU (50%) is the
//               top pipe, and ~45k of it is the P^T->B-frag permlane network
//               + VALU lsum. This round: PV via 2x mfma 16x16x16 per 32-key
//               half — the S-MFMA C-layout (D[key=quad*4+r][q=l15]) IS the
//               16x16x16 B-frag layout (B[k=quad*4+j][n=l15]), so P needs
//               only 4 cvt_pkrtz packs, no cross-lane at all. lsum via
//               ones-MFMA (K-dim sum also removes the epilogue shfl reduce).
//               Matrix cycles unchanged (2x count, half K); V reads become
//               8x ds_read_b64 (same LDS cycles, 2-way-free banks).
//               NOTE: K=16 legacy builtin is spelled ...16x16x16f16 (no
//               underscore) on this ROCm — r9 failed on that token alone.
//   k_merge   : sum 4 key-split f16 partials, scale by 1/lsum -> Ows f16
//   k_oproj   : GEMM 256x512x4096 + bias + residual -> fp32 out
//
// MFMA 16x16x32 layouts (HW-verified per guide):
//   A-frag: lane holds A[m=lane&15][k=quad*8+j], j=0..7
//   B-frag: lane holds B[k=quad*8+j][n=lane&15]
//   C/D   : lane holds D[row=quad*4+reg][col=lane&15], reg=0..3
// MFMA 16x16x16 layouts:
//   A-frag: lane holds A[m=lane&15][k=quad*4+j], j=0..3 (2 VGPR)
//   B-frag: lane holds B[k=quad*4+j][n=lane&15]          (2 VGPR)
//   C/D   : same as 16x16x32 (shape-determined)

#define NPIX 4096
#define CIN 256
#define INNER 512
#define NHEAD 8
#define DH 64

typedef _Float16 f16;
typedef __attribute__((ext_vector_type(8))) _Float16 f16x8;
typedef __attribute__((ext_vector_type(4))) _Float16 f16x4;
typedef __attribute__((ext_vector_type(4))) float f32x4;

static __device__ __forceinline__ f32x4 mfma_f16(f16x8 a, f16x8 b, f32x4 c) {
  return __builtin_amdgcn_mfma_f32_16x16x32_f16(a, b, c, 0, 0, 0);
}

static __device__ __forceinline__ f32x4 mfma16(f16x4 a, f16x4 b, f32x4 c) {
  return __builtin_amdgcn_mfma_f32_16x16x16f16(a, b, c, 0, 0, 0);
}

static __device__ __forceinline__ unsigned pk2(float lo, float hi) {
  return __builtin_bit_cast(unsigned, __builtin_amdgcn_cvt_pkrtz(lo, hi));
}

// async global->LDS, 16 B per lane; LDS dest = wave-uniform base + lane*16
static __device__ __forceinline__ void gload_lds16(const void* g, void* l) {
  __builtin_amdgcn_global_load_lds(
      (const __attribute__((address_space(1))) unsigned*)g,
      (__attribute__((address_space(3))) unsigned*)l, 16, 0, 0);
}

// ---------------- K0: fused RMSNorm + weight cvt ----------------
// blocks [0,512): rmsnorm, 8 pixels each. blocks [512,2560): fp32->f16 cvt.
__global__ __launch_bounds__(256) void k_prep(
    const float* __restrict__ x, const float* __restrict__ w,
    float* __restrict__ xn, f16* __restrict__ xnT,
    const float* __restrict__ w1, int n1,
    const float* __restrict__ w2, int n2, f16* __restrict__ wh) {
  const int b = blockIdx.x;
  if (b < NPIX / 8) {
    const int pi = threadIdx.x & 7, cs = threadIdx.x >> 3;  // 8 px x 32 ch-grp
    const int p = b * 8 + pi;
    __shared__ float red[32][8];
    float xv[8];
    float ss = 0.f;
#pragma unroll
    for (int i = 0; i < 8; ++i) {
      xv[i] = x[(cs * 8 + i) * NPIX + p];
      ss += xv[i] * xv[i];
    }
    red[cs][pi] = ss;
    __syncthreads();
    float tot = 0.f;
#pragma unroll
    for (int s = 0; s < 32; ++s) tot += red[s][pi];
    float inv = 16.0f / fmaxf(sqrtf(tot), 1e-12f);  // sqrt(256)=16
    union { f16x8 v; f16 h[8]; } hv;
#pragma unroll
    for (int i = 0; i < 8; ++i) {
      int c = cs * 8 + i;
      float v = xv[i] * inv * w[c];
      xn[c * NPIX + p] = v;
      hv.h[i] = (f16)v;
    }
    *(f16x8*)(xnT + (size_t)p * CIN + cs * 8) = hv.v;
  } else {
    int i = (b - NPIX / 8) * 256 + threadIdx.x;
    if (i < n1) wh[i] = (f16)w1[i];
    else if (i < n1 + n2) wh[i] = (f16)w2[i - n1];
  }
}

// ---------------- K2: QKV GEMM, wave tile 32x64 ----------------
__global__ __launch_bounds__(256) void k_qkv(const f16* __restrict__ wqkv,
                                             const f16* __restrict__ xnT,
                                             f16* __restrict__ qT,
                                             f16* __restrict__ kT,
                                             f16* __restrict__ vv) {
  const int lane = threadIdx.x & 63, wave = threadIdx.x >> 6;
  const int l15 = lane & 15, quad = lane >> 4;
  const int obase = blockIdx.y * 64 + (wave >> 1) * 32;
  const int pbase = blockIdx.x * 128 + (wave & 1) * 64;
  const int sect = blockIdx.y >> 3;  // 0=q, 1=k, 2=v
  f32x4 acc[8];
#pragma unroll
  for (int i = 0; i < 8; ++i) acc[i] = (f32x4){0.f, 0.f, 0.f, 0.f};
#pragma unroll
  for (int kc = 0; kc < CIN / 32; ++kc) {
    f16x8 af[2], bfr[4];
#pragma unroll
    for (int oc = 0; oc < 2; ++oc)
      af[oc] = *(const f16x8*)(wqkv + (size_t)(obase + oc * 16 + l15) * CIN + kc * 32 + quad * 8);
#pragma unroll
    for (int pc = 0; pc < 4; ++pc)
      bfr[pc] = *(const f16x8*)(xnT + (size_t)(pbase + pc * 16 + l15) * CIN + kc * 32 + quad * 8);
    if (sect < 2) {
#pragma unroll
      for (int pc = 0; pc < 4; ++pc)
#pragma unroll
        for (int oc = 0; oc < 2; ++oc)
          acc[pc * 2 + oc] = mfma_f16(bfr[pc], af[oc], acc[pc * 2 + oc]);
    } else {
#pragma unroll
      for (int oc = 0; oc < 2; ++oc)
#pragma unroll
        for (int pc = 0; pc < 4; ++pc)
          acc[oc * 4 + pc] = mfma_f16(af[oc], bfr[pc], acc[oc * 4 + pc]);
    }
  }
  if (sect < 2) {
    f16* dst = (sect == 0) ? qT : kT;
    const float sc = (sect == 0) ? 0.18033688f : 1.0f;  // 0.125*log2(e)
    const int head = blockIdx.y & 7;
    const int dd = (wave >> 1) * 32;
#pragma unroll
    for (int pc = 0; pc < 4; ++pc)
#pragma unroll
      for (int oc = 0; oc < 2; ++oc)
#pragma unroll
        for (int r = 0; r < 4; ++r) {
          int p = pbase + pc * 16 + quad * 4 + r;
          dst[((size_t)(head << 12) + p) * DH + dd + oc * 16 + l15] =
              (f16)(acc[pc * 2 + oc][r] * sc);
        }
  } else {
#pragma unroll
    for (int oc = 0; oc < 2; ++oc)
#pragma unroll
      for (int r = 0; r < 4; ++r) {
        int o = obase + oc * 16 + quad * 4 + r - 2 * INNER;
#pragma unroll
        for (int pc = 0; pc < 4; ++pc)
          vv[(size_t)o * NPIX + pbase + pc * 16 + l15] = (f16)acc[oc * 4 + pc][r];
      }
  }
}

// ---------------- K3: flash attention (LDS-staged K/V, q-split waves) --------
// grid 1024 x 256 threads. bid -> head = bid&7 (one head per XCD L2), split =
// (bid>>3)&3 (key quarter), qb = bid>>5 (0..31). Block: 4 waves x 32 q; keys
// [split*1024, +1024) staged through LDS in 16 double-buffered 64-key chunks.
// LDS swizzle conflict-free (r5 PMC: 0). PV + lsum via 16x16x16 MFMAs: the
// S C-layout is directly the K=16 B-frag, so P->B-frag = 4 cvt_pkrtz packs
// (replaces the 22-inst permlane network + 7 lsum adds + epilogue shuffles
// that dominated r6's VALU pipe at ~45k cyc/CU).
__global__ __launch_bounds__(256, 4) void k_attn(const f16* __restrict__ qT,
                                                 const f16* __restrict__ kT,
                                                 const f16* __restrict__ vv,
                                                 f16* __restrict__ Opart,
                                                 float* __restrict__ Lpart) {
  const int bid = blockIdx.x;
  const int head = bid & 7, split = (bid >> 3) & 3, qb = bid >> 5;
  const int tid = threadIdx.x;
  const int wave = tid >> 6, lane = tid & 63;
  const int l15 = lane & 15, quad = lane >> 4;
  const int keybase = split * 1024;

  __shared__ f16 KV[2][8192];  // per buf: [0,4096) = K chunk, [4096,8192) = V

  // Q B-frags: B[k=d][n=q] from qT[head][q][d]
  const int qrow = (head << 12) + qb * 128 + wave * 32;
  f16x8 qf[2][2];
#pragma unroll
  for (int qt = 0; qt < 2; ++qt)
#pragma unroll
    for (int kc = 0; kc < 2; ++kc)
      qf[qt][kc] = *(const f16x8*)(qT + (size_t)(qrow + qt * 16 + l15) * DH + kc * 32 + quad * 8);

  f32x4 o[2][4], ol4[2];
#pragma unroll
  for (int qt = 0; qt < 2; ++qt) {
#pragma unroll
    for (int c = 0; c < 4; ++c) o[qt][c] = (f32x4){0.f, 0.f, 0.f, 0.f};
    ol4[qt] = (f32x4){0.f, 0.f, 0.f, 0.f};
  }

  const int rx = l15 & 7;  // read-side swizzle xor (row&7 == l15&7)
  const f16x4 ones4 = {1.f16, 1.f16, 1.f16, 1.f16};

  // staging pointers: waves 0,1 stage K rows; waves 2,3 stage V rows.
  const int sRow8 = lane >> 3, sCol = lane & 7;
  const f16* sp[4];
  const int step = (wave < 2) ? 64 * DH : 64;  // f16 elements per chunk
#pragma unroll
  for (int j = 0; j < 4; ++j) {
    const int Rb = wave * 4096 + j * 1024;  // LDS byte offset of this region
    if (wave < 2) {
      const int key = (Rb >> 7) + sRow8;  // 0..63
      sp[j] = kT + ((size_t)(head << 12) + keybase + key) * DH + ((sCol ^ (key & 7)) << 3);
    } else {
      const int dd = ((Rb - 8192) >> 7) + sRow8;  // 0..63
      sp[j] = vv + ((size_t)(head * DH) + dd) * NPIX + keybase + ((sCol ^ (dd & 7)) << 3);
    }
  }
  auto stage = [&](int b) {
    char* base = (char*)(&KV[b][0]) + wave * 4096;
#pragma unroll
    for (int j = 0; j < 4; ++j) {
      gload_lds16(sp[j], base + j * 1024);
      sp[j] += step;
    }
  };

  stage(0);
  __syncthreads();

  for (int ch = 0; ch < 16; ++ch) {
    const int b = ch & 1;
    if (ch < 15) stage(b ^ 1);  // issue early; drains under compute
    const f16* Kb = &KV[b][0];
    const f16* Vb = &KV[b][4096];
#pragma unroll
    for (int h = 0; h < 2; ++h) {  // two 32-key iterations per chunk
      // K frags (16x16x32 A-layout): rows key, 16B col swizzled
      f16x8 kf[2][2];
#pragma unroll
      for (int nc = 0; nc < 2; ++nc) {
        const int key = h * 32 + nc * 16 + l15;
#pragma unroll
        for (int kc = 0; kc < 2; ++kc)
          kf[nc][kc] = *(const f16x8*)(Kb + key * 64 + (((kc * 4 + quad) ^ rx) << 3));
      }
      // V frags (16x16x16 A-layout): lane holds V^T[d=c*16+l15]
      // [key = h*32 + nc*16 + quad*4 + j], j=0..3 -> 8B reads.
      // byte col = h*64+nc*32+quad*8 -> 16B block jb = h*4+nc*2+(quad>>1),
      // sub-8B = (quad&1)*8; swizzled 16B block = jb ^ (dd&7) = jb ^ rx.
      f16x4 vf[2][4];
#pragma unroll
      for (int nc = 0; nc < 2; ++nc) {
        const int jb = h * 4 + nc * 2 + (quad >> 1);
        const int sub4 = (quad & 1) << 2;  // f16 elems
#pragma unroll
        for (int c = 0; c < 4; ++c) {
          const int dd = c * 16 + l15;
          vf[nc][c] = *(const f16x4*)(Vb + dd * 64 + (((jb ^ rx)) << 3) + sub4);
        }
      }
#pragma unroll
      for (int qt = 0; qt < 2; ++qt) {
        // S^T[key][q] = K @ Q'^T (q pre-scaled; C row=key=quad*4+r, col=q=l15)
        f32x4 s0 = mfma_f16(kf[0][0], qf[qt][0], (f32x4){0.f, 0.f, 0.f, 0.f});
        s0 = mfma_f16(kf[0][1], qf[qt][1], s0);
        f32x4 s1 = mfma_f16(kf[1][0], qf[qt][0], (f32x4){0.f, 0.f, 0.f, 0.f});
        s1 = mfma_f16(kf[1][1], qf[qt][1], s1);
        // p = exp2(s'), no max subtraction (|s'| << 1)
        float p0[4], p1[4];
#pragma unroll
        for (int r = 0; r < 4; ++r) {
          p0[r] = __builtin_amdgcn_exp2f(s0[r]);
          p1[r] = __builtin_amdgcn_exp2f(s1[r]);
        }
        // S C-layout == 16x16x16 B-frag (k=key=quad*4+j, n=q=l15):
        // pack to f16 pairs and feed PV directly. No cross-lane ops.
        union { f16x4 v; unsigned u[2]; } pf0, pf1;
        pf0.u[0] = pk2(p0[0], p0[1]);
        pf0.u[1] = pk2(p0[2], p0[3]);
        pf1.u[0] = pk2(p1[0], p1[1]);
        pf1.u[1] = pk2(p1[2], p1[3]);
        // O^T[d][q] += V^T @ P^T  (two K=16 MFMAs per 32-key half)
#pragma unroll
        for (int c = 0; c < 4; ++c) {
          o[qt][c] = mfma16(vf[0][c], pf0.v, o[qt][c]);
          o[qt][c] = mfma16(vf[1][c], pf1.v, o[qt][c]);
        }
        // lsum via ones-MFMA: D[m][q] = sum_k P[k][q], all rows equal;
        // K-dim covers the keys -> no epilogue cross-lane reduce needed.
        ol4[qt] = mfma16(ones4, pf0.v, ol4[qt]);
        ol4[qt] = mfma16(ones4, pf1.v, ol4[qt]);
      }
    }
    __syncthreads();  // staged writes visible + all waves done with buf b
  }

  // store partials (f16): Opart[split][qinst][d], Lpart[split][qinst]
  // ol4 rows all equal = complete per-q lsum over this wave's keys.
#pragma unroll
  for (int qt = 0; qt < 2; ++qt) {
#pragma unroll
    for (int c = 0; c < 4; ++c) {
      const size_t off =
          ((size_t)split * 32768 + qrow + qt * 16 + l15) * 64 + c * 16 + quad * 4;
      f16x4 hv = {(f16)o[qt][c][0], (f16)o[qt][c][1], (f16)o[qt][c][2],
                  (f16)o[qt][c][3]};
      *(f16x4*)(Opart + off) = hv;
    }
    if (quad == 0) Lpart[split * 32768 + qrow + qt * 16 + l15] = ol4[qt][0];
  }
}

// ---------------- K3b: merge 4 key-split f16 partials ----------------
__global__ __launch_bounds__(256) void k_merge(const f16* __restrict__ Opart,
                                               const float* __restrict__ Lpart,
                                               f16* __restrict__ Ows) {
  const int tg = blockIdx.x * 256 + threadIdx.x;
  const int qi = tg >> 2;
  const size_t base = (size_t)tg * 16;
  float acc[16];
#pragma unroll
  for (int i = 0; i < 16; ++i) acc[i] = 0.f;
  float L = 0.f;
#pragma unroll
  for (int s = 0; s < 4; ++s) {
    const f16x8* ph = (const f16x8*)(Opart + (size_t)s * (32768 * 64) + base);
    f16x8 v0 = ph[0], v1 = ph[1];
#pragma unroll
    for (int i = 0; i < 8; ++i) {
      acc[i] += (float)v0[i];
      acc[8 + i] += (float)v1[i];
    }
    L += Lpart[s * 32768 + qi];
  }
  const float rL = 1.0f / L;
  union { f16x8 v[2]; f16 h[16]; } hv;
#pragma unroll
  for (int i = 0; i < 16; ++i) hv.h[i] = (f16)(acc[i] * rL);
  *(f16x8*)(Ows + base) = hv.v[0];
  *(f16x8*)(Ows + base + 8) = hv.v[1];
}

// ---------------- K4: out projection + bias + residual ----------------
__global__ __launch_bounds__(256) void k_oproj(const f16* __restrict__ wout,
                                               const f16* __restrict__ Ows,
                                               const float* __restrict__ bout,
                                               const float* __restrict__ xn,
                                               float* __restrict__ out) {
  const int lane = threadIdx.x & 63, wave = threadIdx.x >> 6;
  const int l15 = lane & 15, quad = lane >> 4;
  const int mbase = blockIdx.y * 32 + (wave >> 1) * 16;
  const int pbase = blockIdx.x * 64 + (wave & 1) * 32;
  f32x4 acc[2];
  acc[0] = (f32x4){0.f, 0.f, 0.f, 0.f};
  acc[1] = (f32x4){0.f, 0.f, 0.f, 0.f};
#pragma unroll
  for (int kc = 0; kc < INNER / 32; ++kc) {
    f16x8 af = *(const f16x8*)(wout + (size_t)(mbase + l15) * INNER + kc * 32 + quad * 8);
    int i0 = kc * 32 + quad * 8;
    int head = i0 >> 6, d0 = i0 & 63;
#pragma unroll
    for (int pc = 0; pc < 2; ++pc) {
      f16x8 bfr = *(const f16x8*)(Ows + ((size_t)(head << 12) + pbase + pc * 16 + l15) * DH + d0);
      acc[pc] = mfma_f16(af, bfr, acc[pc]);
    }
  }
#pragma unroll
  for (int pc = 0; pc < 2; ++pc)
#pragma unroll
    for (int r = 0; r < 4; ++r) {
      int c = mbase + quad * 4 + r, p = pbase + pc * 16 + l15;
      out[c * NPIX + p] = acc[pc][r] + bout[c] + xn[c * NPIX + p];
    }
}

extern "C" void kernel_launch(void* const* d_in, const int* in_sizes, int n_in,
                              void* d_out, int out_size, void* d_ws, size_t ws_size,
                              hipStream_t stream) {
  (void)in_sizes; (void)n_in; (void)out_size; (void)ws_size;
  const float* x      = (const float*)d_in[0];
  const float* norm_w = (const float*)d_in[1];
  const float* w_qkv  = (const float*)d_in[2];
  const float* w_out  = (const float*)d_in[3];
  const float* b_out  = (const float*)d_in[4];
  float* out = (float*)d_out;

  char* ws = (char*)d_ws;
  float* xn    = (float*)(ws);                 // 4 MB
  f16* xnT     = (f16*)(ws + (4u << 20));      // 2 MB
  f16* qT      = (f16*)(ws + (6u << 20));      // 4 MB  [head][p][d], pre-scaled
  f16* kT      = (f16*)(ws + (10u << 20));     // 4 MB  [head][p][d]
  f16* vv      = (f16*)(ws + (14u << 20));     // 4 MB  [head*64+d][p]
  f16* Ows     = (f16*)(ws + (18u << 20));     // 4 MB  [head][p][d]
  f16* wqkv_h  = (f16*)(ws + (22u << 20));             // 0.75 MB
  f16* wout_h  = (f16*)(ws + (22u << 20) + 786432);    // 0.25 MB
  f16* Opart   = (f16*)(ws + (24u << 20));             // 16 MB [4][32768][64]
  float* Lpart = (float*)(ws + (40u << 20));           // 0.5 MB [4][32768]

  const int n1 = 3 * INNER * CIN, n2 = CIN * INNER;
  hipLaunchKernelGGL(k_prep, dim3(NPIX / 8 + (n1 + n2 + 255) / 256), dim3(256), 0,
                     stream, x, norm_w, xn, xnT, w_qkv, n1, w_out, n2, wqkv_h);
  hipLaunchKernelGGL(k_qkv, dim3(NPIX / 128, 1536 / 64), dim3(256), 0, stream,
                     wqkv_h, xnT, qT, kT, vv);
  hipLaunchKernelGGL(k_attn, dim3(1024), dim3(256), 0, stream,
                     qT, kT, vv, Opart, Lpart);
  hipLaunchKernelGGL(k_merge, dim3(512), dim3(256), 0, stream, Opart, Lpart, Ows);
  hipLaunchKernelGGL(k_oproj, dim3(NPIX / 64, CIN / 32), dim3(256), 0, stream,
                     wout_h, Ows, b_out, xn, out);
}

// Round 13
// 150.869 us; speedup vs baseline: 8.4113x; 1.0143x over previous
//
#include <hip/hip_runtime.h>

// FullAttention fused block on gfx950. fp32 harness I/O, fp16 MFMA internally.
//
// Pipeline (5 launches):
//   k_prep    : fused [rmsnorm: x[C][N] -> xn fp32 + xnT[N][C] f16] +
//               [w_qkv,w_out fp32 -> f16]; block-range split
//   k_qkv     : GEMM 1536x256x4096 -> qT/kT [head][p][d] f16 (q pre-scaled by
//               0.125*log2e), vv [d'][p] f16
//   k_attn    : flash attention. r10 PMC: 16x16x16 MFMA costs the same issue
//               slots as 16x16x32 (MfmaUtil 27->47% at 14 vs 8 slots/qt-iter)
//               -> matrix is now the top pipe (56k cyc/CU). This round: drop
//               the 2 ones-MFMA lsum slots (matrix -14%), lsum via VALU adds
//               + deferred quad shfl-reduce (r6 mechanism). Keeps the K=16 PV
//               (S C-layout == K=16 B-frag: 4 cvt_pkrtz, no cross-lane).
//               V b64 4-way bank conflict is structural (8B-half select is
//               data-determined; 16B-granular gload_lds swizzle can't reach
//               it; reg-staging just moves the 4-way to the write side).
//   k_merge   : sum 4 key-split f16 partials, scale by 1/lsum -> Ows f16
//   k_oproj   : GEMM 256x512x4096 + bias + residual -> fp32 out
//
// MFMA 16x16x32 layouts (HW-verified per guide):
//   A-frag: lane holds A[m=lane&15][k=quad*8+j], j=0..7
//   B-frag: lane holds B[k=quad*8+j][n=lane&15]
//   C/D   : lane holds D[row=quad*4+reg][col=lane&15], reg=0..3
// MFMA 16x16x16 layouts:
//   A-frag: lane holds A[m=lane&15][k=quad*4+j], j=0..3 (2 VGPR)
//   B-frag: lane holds B[k=quad*4+j][n=lane&15]          (2 VGPR)
//   C/D   : same as 16x16x32 (shape-determined)

#define NPIX 4096
#define CIN 256
#define INNER 512
#define NHEAD 8
#define DH 64

typedef _Float16 f16;
typedef __attribute__((ext_vector_type(8))) _Float16 f16x8;
typedef __attribute__((ext_vector_type(4))) _Float16 f16x4;
typedef __attribute__((ext_vector_type(4))) float f32x4;

static __device__ __forceinline__ f32x4 mfma_f16(f16x8 a, f16x8 b, f32x4 c) {
  return __builtin_amdgcn_mfma_f32_16x16x32_f16(a, b, c, 0, 0, 0);
}

static __device__ __forceinline__ f32x4 mfma16(f16x4 a, f16x4 b, f32x4 c) {
  return __builtin_amdgcn_mfma_f32_16x16x16f16(a, b, c, 0, 0, 0);
}

static __device__ __forceinline__ unsigned pk2(float lo, float hi) {
  return __builtin_bit_cast(unsigned, __builtin_amdgcn_cvt_pkrtz(lo, hi));
}

// async global->LDS, 16 B per lane; LDS dest = wave-uniform base + lane*16
static __device__ __forceinline__ void gload_lds16(const void* g, void* l) {
  __builtin_amdgcn_global_load_lds(
      (const __attribute__((address_space(1))) unsigned*)g,
      (__attribute__((address_space(3))) unsigned*)l, 16, 0, 0);
}

// ---------------- K0: fused RMSNorm + weight cvt ----------------
// blocks [0,512): rmsnorm, 8 pixels each. blocks [512,2560): fp32->f16 cvt.
__global__ __launch_bounds__(256) void k_prep(
    const float* __restrict__ x, const float* __restrict__ w,
    float* __restrict__ xn, f16* __restrict__ xnT,
    const float* __restrict__ w1, int n1,
    const float* __restrict__ w2, int n2, f16* __restrict__ wh) {
  const int b = blockIdx.x;
  if (b < NPIX / 8) {
    const int pi = threadIdx.x & 7, cs = threadIdx.x >> 3;  // 8 px x 32 ch-grp
    const int p = b * 8 + pi;
    __shared__ float red[32][8];
    float xv[8];
    float ss = 0.f;
#pragma unroll
    for (int i = 0; i < 8; ++i) {
      xv[i] = x[(cs * 8 + i) * NPIX + p];
      ss += xv[i] * xv[i];
    }
    red[cs][pi] = ss;
    __syncthreads();
    float tot = 0.f;
#pragma unroll
    for (int s = 0; s < 32; ++s) tot += red[s][pi];
    float inv = 16.0f / fmaxf(sqrtf(tot), 1e-12f);  // sqrt(256)=16
    union { f16x8 v; f16 h[8]; } hv;
#pragma unroll
    for (int i = 0; i < 8; ++i) {
      int c = cs * 8 + i;
      float v = xv[i] * inv * w[c];
      xn[c * NPIX + p] = v;
      hv.h[i] = (f16)v;
    }
    *(f16x8*)(xnT + (size_t)p * CIN + cs * 8) = hv.v;
  } else {
    int i = (b - NPIX / 8) * 256 + threadIdx.x;
    if (i < n1) wh[i] = (f16)w1[i];
    else if (i < n1 + n2) wh[i] = (f16)w2[i - n1];
  }
}

// ---------------- K2: QKV GEMM, wave tile 32x64 ----------------
__global__ __launch_bounds__(256) void k_qkv(const f16* __restrict__ wqkv,
                                             const f16* __restrict__ xnT,
                                             f16* __restrict__ qT,
                                             f16* __restrict__ kT,
                                             f16* __restrict__ vv) {
  const int lane = threadIdx.x & 63, wave = threadIdx.x >> 6;
  const int l15 = lane & 15, quad = lane >> 4;
  const int obase = blockIdx.y * 64 + (wave >> 1) * 32;
  const int pbase = blockIdx.x * 128 + (wave & 1) * 64;
  const int sect = blockIdx.y >> 3;  // 0=q, 1=k, 2=v
  f32x4 acc[8];
#pragma unroll
  for (int i = 0; i < 8; ++i) acc[i] = (f32x4){0.f, 0.f, 0.f, 0.f};
#pragma unroll
  for (int kc = 0; kc < CIN / 32; ++kc) {
    f16x8 af[2], bfr[4];
#pragma unroll
    for (int oc = 0; oc < 2; ++oc)
      af[oc] = *(const f16x8*)(wqkv + (size_t)(obase + oc * 16 + l15) * CIN + kc * 32 + quad * 8);
#pragma unroll
    for (int pc = 0; pc < 4; ++pc)
      bfr[pc] = *(const f16x8*)(xnT + (size_t)(pbase + pc * 16 + l15) * CIN + kc * 32 + quad * 8);
    if (sect < 2) {
#pragma unroll
      for (int pc = 0; pc < 4; ++pc)
#pragma unroll
        for (int oc = 0; oc < 2; ++oc)
          acc[pc * 2 + oc] = mfma_f16(bfr[pc], af[oc], acc[pc * 2 + oc]);
    } else {
#pragma unroll
      for (int oc = 0; oc < 2; ++oc)
#pragma unroll
        for (int pc = 0; pc < 4; ++pc)
          acc[oc * 4 + pc] = mfma_f16(af[oc], bfr[pc], acc[oc * 4 + pc]);
    }
  }
  if (sect < 2) {
    f16* dst = (sect == 0) ? qT : kT;
    const float sc = (sect == 0) ? 0.18033688f : 1.0f;  // 0.125*log2(e)
    const int head = blockIdx.y & 7;
    const int dd = (wave >> 1) * 32;
#pragma unroll
    for (int pc = 0; pc < 4; ++pc)
#pragma unroll
      for (int oc = 0; oc < 2; ++oc)
#pragma unroll
        for (int r = 0; r < 4; ++r) {
          int p = pbase + pc * 16 + quad * 4 + r;
          dst[((size_t)(head << 12) + p) * DH + dd + oc * 16 + l15] =
              (f16)(acc[pc * 2 + oc][r] * sc);
        }
  } else {
#pragma unroll
    for (int oc = 0; oc < 2; ++oc)
#pragma unroll
      for (int r = 0; r < 4; ++r) {
        int o = obase + oc * 16 + quad * 4 + r - 2 * INNER;
#pragma unroll
        for (int pc = 0; pc < 4; ++pc)
          vv[(size_t)o * NPIX + pbase + pc * 16 + l15] = (f16)acc[oc * 4 + pc][r];
      }
  }
}

// ---------------- K3: flash attention (LDS-staged K/V, q-split waves) --------
// grid 1024 x 256 threads. bid -> head = bid&7 (one head per XCD L2), split =
// (bid>>3)&3 (key quarter), qb = bid>>5 (0..31). Block: 4 waves x 32 q; keys
// [split*1024, +1024) staged through LDS in 16 double-buffered 64-key chunks.
// PV via K=16 MFMAs fed directly from the S C-layout (4 cvt_pkrtz, zero
// cross-lane); lsum via VALU adds + deferred quad shfl-reduce (ones-MFMA
// dropped: K=16 MFMA costs full issue slots, r10 PMC).
__global__ __launch_bounds__(256, 4) void k_attn(const f16* __restrict__ qT,
                                                 const f16* __restrict__ kT,
                                                 const f16* __restrict__ vv,
                                                 f16* __restrict__ Opart,
                                                 float* __restrict__ Lpart) {
  const int bid = blockIdx.x;
  const int head = bid & 7, split = (bid >> 3) & 3, qb = bid >> 5;
  const int tid = threadIdx.x;
  const int wave = tid >> 6, lane = tid & 63;
  const int l15 = lane & 15, quad = lane >> 4;
  const int keybase = split * 1024;

  __shared__ f16 KV[2][8192];  // per buf: [0,4096) = K chunk, [4096,8192) = V

  // Q B-frags: B[k=d][n=q] from qT[head][q][d]
  const int qrow = (head << 12) + qb * 128 + wave * 32;
  f16x8 qf[2][2];
#pragma unroll
  for (int qt = 0; qt < 2; ++qt)
#pragma unroll
    for (int kc = 0; kc < 2; ++kc)
      qf[qt][kc] = *(const f16x8*)(qT + (size_t)(qrow + qt * 16 + l15) * DH + kc * 32 + quad * 8);

  f32x4 o[2][4];
  float ol[2] = {0.f, 0.f};
#pragma unroll
  for (int qt = 0; qt < 2; ++qt)
#pragma unroll
    for (int c = 0; c < 4; ++c) o[qt][c] = (f32x4){0.f, 0.f, 0.f, 0.f};

  const int rx = l15 & 7;  // read-side swizzle xor (row&7 == l15&7)

  // staging pointers: waves 0,1 stage K rows; waves 2,3 stage V rows.
  const int sRow8 = lane >> 3, sCol = lane & 7;
  const f16* sp[4];
  const int step = (wave < 2) ? 64 * DH : 64;  // f16 elements per chunk
#pragma unroll
  for (int j = 0; j < 4; ++j) {
    const int Rb = wave * 4096 + j * 1024;  // LDS byte offset of this region
    if (wave < 2) {
      const int key = (Rb >> 7) + sRow8;  // 0..63
      sp[j] = kT + ((size_t)(head << 12) + keybase + key) * DH + ((sCol ^ (key & 7)) << 3);
    } else {
      const int dd = ((Rb - 8192) >> 7) + sRow8;  // 0..63
      sp[j] = vv + ((size_t)(head * DH) + dd) * NPIX + keybase + ((sCol ^ (dd & 7)) << 3);
    }
  }
  auto stage = [&](int b) {
    char* base = (char*)(&KV[b][0]) + wave * 4096;
#pragma unroll
    for (int j = 0; j < 4; ++j) {
      gload_lds16(sp[j], base + j * 1024);
      sp[j] += step;
    }
  };

  stage(0);
  __syncthreads();

  for (int ch = 0; ch < 16; ++ch) {
    const int b = ch & 1;
    if (ch < 15) stage(b ^ 1);  // issue early; drains under compute
    const f16* Kb = &KV[b][0];
    const f16* Vb = &KV[b][4096];
#pragma unroll
    for (int h = 0; h < 2; ++h) {  // two 32-key iterations per chunk
      // K frags (16x16x32 A-layout): rows key, 16B col swizzled
      f16x8 kf[2][2];
#pragma unroll
      for (int nc = 0; nc < 2; ++nc) {
        const int key = h * 32 + nc * 16 + l15;
#pragma unroll
        for (int kc = 0; kc < 2; ++kc)
          kf[nc][kc] = *(const f16x8*)(Kb + key * 64 + (((kc * 4 + quad) ^ rx) << 3));
      }
      // V frags (16x16x16 A-layout): lane holds V^T[d=c*16+l15]
      // [key = h*32 + nc*16 + quad*4 + j], j=0..3 -> 8B reads.
      f16x4 vf[2][4];
#pragma unroll
      for (int nc = 0; nc < 2; ++nc) {
        const int jb = h * 4 + nc * 2 + (quad >> 1);
        const int sub4 = (quad & 1) << 2;  // f16 elems
#pragma unroll
        for (int c = 0; c < 4; ++c) {
          const int dd = c * 16 + l15;
          vf[nc][c] = *(const f16x4*)(Vb + dd * 64 + (((jb ^ rx)) << 3) + sub4);
        }
      }
#pragma unroll
      for (int qt = 0; qt < 2; ++qt) {
        // S^T[key][q] = K @ Q'^T (q pre-scaled; C row=key=quad*4+r, col=q=l15)
        f32x4 s0 = mfma_f16(kf[0][0], qf[qt][0], (f32x4){0.f, 0.f, 0.f, 0.f});
        s0 = mfma_f16(kf[0][1], qf[qt][1], s0);
        f32x4 s1 = mfma_f16(kf[1][0], qf[qt][0], (f32x4){0.f, 0.f, 0.f, 0.f});
        s1 = mfma_f16(kf[1][1], qf[qt][1], s1);
        // p = exp2(s'), no max subtraction (|s'| << 1)
        float p0[4], p1[4];
#pragma unroll
        for (int r = 0; r < 4; ++r) {
          p0[r] = __builtin_amdgcn_exp2f(s0[r]);
          p1[r] = __builtin_amdgcn_exp2f(s1[r]);
        }
        // per-lane lsum partial (8 keys for q=l15); quad-reduce deferred
        ol[qt] += ((p0[0] + p0[1]) + (p0[2] + p0[3])) +
                  ((p1[0] + p1[1]) + (p1[2] + p1[3]));
        // S C-layout == 16x16x16 B-frag (k=key=quad*4+j, n=q=l15):
        // pack to f16 pairs and feed PV directly. No cross-lane ops.
        union { f16x4 v; unsigned u[2]; } pf0, pf1;
        pf0.u[0] = pk2(p0[0], p0[1]);
        pf0.u[1] = pk2(p0[2], p0[3]);
        pf1.u[0] = pk2(p1[0], p1[1]);
        pf1.u[1] = pk2(p1[2], p1[3]);
        // O^T[d][q] += V^T @ P^T  (two K=16 MFMAs per 32-key half)
#pragma unroll
        for (int c = 0; c < 4; ++c) {
          o[qt][c] = mfma16(vf[0][c], pf0.v, o[qt][c]);
          o[qt][c] = mfma16(vf[1][c], pf1.v, o[qt][c]);
        }
      }
    }
    __syncthreads();  // staged writes visible + all waves done with buf b
  }

  // deferred lsum quad-reduce
#pragma unroll
  for (int qt = 0; qt < 2; ++qt) {
    ol[qt] += __shfl_xor(ol[qt], 16);
    ol[qt] += __shfl_xor(ol[qt], 32);
  }

  // store partials (f16): Opart[split][qinst][d], Lpart[split][qinst]
#pragma unroll
  for (int qt = 0; qt < 2; ++qt) {
#pragma unroll
    for (int c = 0; c < 4; ++c) {
      const size_t off =
          ((size_t)split * 32768 + qrow + qt * 16 + l15) * 64 + c * 16 + quad * 4;
      f16x4 hv = {(f16)o[qt][c][0], (f16)o[qt][c][1], (f16)o[qt][c][2],
                  (f16)o[qt][c][3]};
      *(f16x4*)(Opart + off) = hv;
    }
    if (quad == 0) Lpart[split * 32768 + qrow + qt * 16 + l15] = ol[qt];
  }
}

// ---------------- K3b: merge 4 key-split f16 partials ----------------
__global__ __launch_bounds__(256) void k_merge(const f16* __restrict__ Opart,
                                               const float* __restrict__ Lpart,
                                               f16* __restrict__ Ows) {
  const int tg = blockIdx.x * 256 + threadIdx.x;
  const int qi = tg >> 2;
  const size_t base = (size_t)tg * 16;
  float acc[16];
#pragma unroll
  for (int i = 0; i < 16; ++i) acc[i] = 0.f;
  float L = 0.f;
#pragma unroll
  for (int s = 0; s < 4; ++s) {
    const f16x8* ph = (const f16x8*)(Opart + (size_t)s * (32768 * 64) + base);
    f16x8 v0 = ph[0], v1 = ph[1];
#pragma unroll
    for (int i = 0; i < 8; ++i) {
      acc[i] += (float)v0[i];
      acc[8 + i] += (float)v1[i];
    }
    L += Lpart[s * 32768 + qi];
  }
  const float rL = 1.0f / L;
  union { f16x8 v[2]; f16 h[16]; } hv;
#pragma unroll
  for (int i = 0; i < 16; ++i) hv.h[i] = (f16)(acc[i] * rL);
  *(f16x8*)(Ows + base) = hv.v[0];
  *(f16x8*)(Ows + base + 8) = hv.v[1];
}

// ---------------- K4: out projection + bias + residual ----------------
__global__ __launch_bounds__(256) void k_oproj(const f16* __restrict__ wout,
                                               const f16* __restrict__ Ows,
                                               const float* __restrict__ bout,
                                               const float* __restrict__ xn,
                                               float* __restrict__ out) {
  const int lane = threadIdx.x & 63, wave = threadIdx.x >> 6;
  const int l15 = lane & 15, quad = lane >> 4;
  const int mbase = blockIdx.y * 32 + (wave >> 1) * 16;
  const int pbase = blockIdx.x * 64 + (wave & 1) * 32;
  f32x4 acc[2];
  acc[0] = (f32x4){0.f, 0.f, 0.f, 0.f};
  acc[1] = (f32x4){0.f, 0.f, 0.f, 0.f};
#pragma unroll
  for (int kc = 0; kc < INNER / 32; ++kc) {
    f16x8 af = *(const f16x8*)(wout + (size_t)(mbase + l15) * INNER + kc * 32 + quad * 8);
    int i0 = kc * 32 + quad * 8;
    int head = i0 >> 6, d0 = i0 & 63;
#pragma unroll
    for (int pc = 0; pc < 2; ++pc) {
      f16x8 bfr = *(const f16x8*)(Ows + ((size_t)(head << 12) + pbase + pc * 16 + l15) * DH + d0);
      acc[pc] = mfma_f16(af, bfr, acc[pc]);
    }
  }
#pragma unroll
  for (int pc = 0; pc < 2; ++pc)
#pragma unroll
    for (int r = 0; r < 4; ++r) {
      int c = mbase + quad * 4 + r, p = pbase + pc * 16 + l15;
      out[c * NPIX + p] = acc[pc][r] + bout[c] + xn[c * NPIX + p];
    }
}

extern "C" void kernel_launch(void* const* d_in, const int* in_sizes, int n_in,
                              void* d_out, int out_size, void* d_ws, size_t ws_size,
                              hipStream_t stream) {
  (void)in_sizes; (void)n_in; (void)out_size; (void)ws_size;
  const float* x      = (const float*)d_in[0];
  const float* norm_w = (const float*)d_in[1];
  const float* w_qkv  = (const float*)d_in[2];
  const float* w_out  = (const float*)d_in[3];
  const float* b_out  = (const float*)d_in[4];
  float* out = (float*)d_out;

  char* ws = (char*)d_ws;
  float* xn    = (float*)(ws);                 // 4 MB
  f16* xnT     = (f16*)(ws + (4u << 20));      // 2 MB
  f16* qT      = (f16*)(ws + (6u << 20));      // 4 MB  [head][p][d], pre-scaled
  f16* kT      = (f16*)(ws + (10u << 20));     // 4 MB  [head][p][d]
  f16* vv      = (f16*)(ws + (14u << 20));     // 4 MB  [head*64+d][p]
  f16* Ows     = (f16*)(ws + (18u << 20));     // 4 MB  [head][p][d]
  f16* wqkv_h  = (f16*)(ws + (22u << 20));             // 0.75 MB
  f16* wout_h  = (f16*)(ws + (22u << 20) + 786432);    // 0.25 MB
  f16* Opart   = (f16*)(ws + (24u << 20));             // 16 MB [4][32768][64]
  float* Lpart = (float*)(ws + (40u << 20));           // 0.5 MB [4][32768]

  const int n1 = 3 * INNER * CIN, n2 = CIN * INNER;
  hipLaunchKernelGGL(k_prep, dim3(NPIX / 8 + (n1 + n2 + 255) / 256), dim3(256), 0,
                     stream, x, norm_w, xn, xnT, w_qkv, n1, w_out, n2, wqkv_h);
  hipLaunchKernelGGL(k_qkv, dim3(NPIX / 128, 1536 / 64), dim3(256), 0, stream,
                     wqkv_h, xnT, qT, kT, vv);
  hipLaunchKernelGGL(k_attn, dim3(1024), dim3(256), 0, stream,
                     qT, kT, vv, Opart, Lpart);
  hipLaunchKernelGGL(k_merge, dim3(512), dim3(256), 0, stream, Opart, Lpart, Ows);
  hipLaunchKernelGGL(k_oproj, dim3(NPIX / 64, CIN / 32), dim3(256), 0, stream,
                     wout_h, Ows, b_out, xn, out);
}